// Round 1
// baseline (94.126 us; speedup 1.0000x reference)
//
#include <hip/hip_runtime.h>
#include <math.h>

#define IEPS 1e-8f

__device__ __forceinline__ float cross2(float ax, float ay, float bx, float by) {
    return ax * by - ay * bx;
}

__global__ __launch_bounds__(256) void iou3d_loss_kernel(
    const float* __restrict__ pred,
    const float* __restrict__ target,
    const float* __restrict__ weight,
    float* __restrict__ out,
    int N, float invN)
{
    int i = blockIdx.x * blockDim.x + threadIdx.x;
    float contrib = 0.0f;

    if (i < N) {
        float b1[7], b2[7];
        #pragma unroll
        for (int k = 0; k < 7; ++k) { b1[k] = pred[i * 7 + k]; b2[k] = target[i * 7 + k]; }

        // BEV boxes: (x, y, w=dim3, h=dim4, yaw=dim6)
        float cx1 = b1[0], cy1 = b1[1], w1 = b1[3], h1 = b1[4];
        float cx2 = b2[0], cy2 = b2[1], w2 = b2[3], h2 = b2[4];
        float s1a, c1a, s2a, c2a;
        sincosf(b1[6], &s1a, &c1a);
        sincosf(b2[6], &s2a, &c2a);

        // corners (same order as reference: (-,-), (+,-), (+,+), (-,+))
        const float lox[4] = {-0.5f, 0.5f, 0.5f, -0.5f};
        const float loy[4] = {-0.5f, -0.5f, 0.5f, 0.5f};
        float cxs1[4], cys1[4], cxs2[4], cys2[4];
        #pragma unroll
        for (int k = 0; k < 4; ++k) {
            float sx = lox[k] * w1, sy = loy[k] * h1;
            cxs1[k] = sx * c1a - sy * s1a + cx1;
            cys1[k] = sx * s1a + sy * c1a + cy1;
            float tx = lox[k] * w2, ty = loy[k] * h2;
            cxs2[k] = tx * c2a - ty * s2a + cx2;
            cys2[k] = tx * s2a + ty * c2a + cy2;
        }

        // candidate vertices (order matches reference: edge hits (c1-edge major),
        // then c1 corners in box2, then c2 corners in box1)
        float vx[24], vy[24];
        int nv = 0;

        #pragma unroll
        for (int k = 0; k < 4; ++k) {
            float p1x = cxs1[k], p1y = cys1[k];
            float p2x = cxs1[(k + 1) & 3], p2y = cys1[(k + 1) & 3];
            float d1x = p2x - p1x, d1y = p2y - p1y;
            #pragma unroll
            for (int j = 0; j < 4; ++j) {
                float q1x = cxs2[j], q1y = cys2[j];
                float q2x = cxs2[(j + 1) & 3], q2y = cys2[(j + 1) & 3];
                float d2x = q2x - q1x, d2y = q2y - q1y;
                float den = cross2(d1x, d1y, d2x, d2y);
                if (fabsf(den) > IEPS) {
                    float rx = q1x - p1x, ry = q1y - p1y;
                    float t = cross2(rx, ry, d2x, d2y) / den;
                    float s = cross2(rx, ry, d1x, d1y) / den;
                    if (t >= 0.0f && t <= 1.0f && s >= 0.0f && s <= 1.0f) {
                        vx[nv] = p1x + t * d1x;
                        vy[nv] = p1y + t * d1y;
                        ++nv;
                    }
                }
            }
        }

        // corners of box1 inside box2
        #pragma unroll
        for (int k = 0; k < 4; ++k) {
            float dx = cxs1[k] - cx2, dy = cys1[k] - cy2;
            float lx = dx * c2a + dy * s2a;
            float ly = -dx * s2a + dy * c2a;
            if (fabsf(lx) <= 0.5f * w2 && fabsf(ly) <= 0.5f * h2) {
                vx[nv] = cxs1[k]; vy[nv] = cys1[k]; ++nv;
            }
        }
        // corners of box2 inside box1
        #pragma unroll
        for (int k = 0; k < 4; ++k) {
            float dx = cxs2[k] - cx1, dy = cys2[k] - cy1;
            float lx = dx * c1a + dy * s1a;
            float ly = -dx * s1a + dy * c1a;
            if (fabsf(lx) <= 0.5f * w1 && fabsf(ly) <= 0.5f * h1) {
                vx[nv] = cxs2[k]; vy[nv] = cys2[k]; ++nv;
            }
        }

        float inter2d = 0.0f;
        if (nv >= 3) {
            float mx = 0.0f, my = 0.0f;
            for (int k = 0; k < nv; ++k) { mx += vx[k]; my += vy[k]; }
            float inv_nv = 1.0f / (float)nv;
            mx *= inv_nv; my *= inv_nv;

            float ang[24];
            for (int k = 0; k < nv; ++k) ang[k] = atan2f(vy[k] - my, vx[k] - mx);

            // stable insertion sort by angle (matches stable argsort)
            for (int k = 1; k < nv; ++k) {
                float a = ang[k], x = vx[k], y = vy[k];
                int m = k - 1;
                while (m >= 0 && ang[m] > a) {
                    ang[m + 1] = ang[m]; vx[m + 1] = vx[m]; vy[m + 1] = vy[m];
                    --m;
                }
                ang[m + 1] = a; vx[m + 1] = x; vy[m + 1] = y;
            }

            float ssum = 0.0f;
            for (int k = 0; k < nv; ++k) {
                int n2 = (k + 1 == nv) ? 0 : k + 1;
                ssum += vx[k] * vy[n2] - vy[k] * vx[n2];
            }
            inter2d = 0.5f * fabsf(ssum);
        }

        // z overlap
        float zmax1 = b1[2] + 0.5f * b1[5], zmin1 = b1[2] - 0.5f * b1[5];
        float zmax2 = b2[2] + 0.5f * b2[5], zmin2 = b2[2] - 0.5f * b2[5];
        float zo = fminf(zmax1, zmax2) - fmaxf(zmin1, zmin2);
        zo = fmaxf(zo, 0.0f);

        float inter3d = inter2d * zo;
        float v1 = b1[3] * b1[4] * b1[5];
        float v2 = b2[3] * b2[4] * b2[5];
        float denom = fmaxf(v1 + v2 - inter3d, IEPS);
        float iou = inter3d / denom;

        contrib = weight[i] * (1.0f - iou);
    }

    // wave(64) reduction
    #pragma unroll
    for (int off = 32; off > 0; off >>= 1)
        contrib += __shfl_down(contrib, off);

    __shared__ float sred[4];
    int lane = threadIdx.x & 63;
    int wid  = threadIdx.x >> 6;
    if (lane == 0) sred[wid] = contrib;
    __syncthreads();
    if (threadIdx.x == 0) {
        float s = sred[0] + sred[1] + sred[2] + sred[3];
        atomicAdd(out, s * invN);
    }
}

extern "C" void kernel_launch(void* const* d_in, const int* in_sizes, int n_in,
                              void* d_out, int out_size, void* d_ws, size_t ws_size,
                              hipStream_t stream) {
    const float* pred   = (const float*)d_in[0];
    const float* target = (const float*)d_in[1];
    const float* weight = (const float*)d_in[2];
    float* out = (float*)d_out;

    int N = in_sizes[0] / 7;
    float invN = 1.0f / (float)N;

    hipMemsetAsync(out, 0, sizeof(float), stream);

    int block = 256;
    int grid = (N + block - 1) / block;
    iou3d_loss_kernel<<<grid, block, 0, stream>>>(pred, target, weight, out, N, invN);
}

// Round 2
// 28.275 us; speedup vs baseline: 3.3289x; 3.3289x over previous
//
#include <hip/hip_runtime.h>
#include <math.h>

#define IEPS 1e-8f

// Liang-Barsky half-plane clip update: constraint p*t <= q
__device__ __forceinline__ void clipLB(float p, float q, float& t0, float& t1, bool& ok) {
    if (p < 0.0f)       t0 = fmaxf(t0, q / p);
    else if (p > 0.0f)  t1 = fminf(t1, q / p);
    else if (q < 0.0f)  ok = false;
}

// Clip segment (px,py)->(qx,qy) (global frame) against a rotated rect
// centered at (cx,cy), rotation (ca,sa), half-extents (hw,hh).
// Accumulate cross(A,B) of the surviving directed sub-segment into area2.
__device__ __forceinline__ void edge_contrib(
    float px, float py, float qx, float qy,
    float cx, float cy, float ca, float sa, float hw, float hh,
    float& area2)
{
    // endpoints in rect-local frame
    float dx0 = px - cx, dy0 = py - cy;
    float lx1 =  dx0 * ca + dy0 * sa;
    float ly1 = -dx0 * sa + dy0 * ca;
    float dx1 = qx - cx, dy1 = qy - cy;
    float lx2 =  dx1 * ca + dy1 * sa;
    float ly2 = -dx1 * sa + dy1 * ca;
    float ddx = lx2 - lx1, ddy = ly2 - ly1;

    float t0 = 0.0f, t1 = 1.0f;
    bool ok = true;
    clipLB(-ddx, lx1 + hw, t0, t1, ok);   // x >= -hw
    clipLB( ddx, hw - lx1, t0, t1, ok);   // x <=  hw
    clipLB(-ddy, ly1 + hh, t0, t1, ok);   // y >= -hh
    clipLB( ddy, hh - ly1, t0, t1, ok);   // y <=  hh

    if (ok && t0 < t1) {
        float ex = qx - px, ey = qy - py;
        float ax = px + t0 * ex, ay = py + t0 * ey;
        float bx = px + t1 * ex, by = py + t1 * ey;
        area2 += ax * by - ay * bx;
    }
}

__global__ __launch_bounds__(256) void iou3d_loss_kernel(
    const float* __restrict__ pred,
    const float* __restrict__ target,
    const float* __restrict__ weight,
    float* __restrict__ out,
    int N, float invN)
{
    int i = blockIdx.x * blockDim.x + threadIdx.x;
    float contrib = 0.0f;

    if (i < N) {
        float b1[7], b2[7];
        #pragma unroll
        for (int k = 0; k < 7; ++k) { b1[k] = pred[i * 7 + k]; b2[k] = target[i * 7 + k]; }

        float cx1 = b1[0], cy1 = b1[1], w1 = b1[3], h1 = b1[4];
        float cx2 = b2[0], cy2 = b2[1], w2 = b2[3], h2 = b2[4];
        float s1a, c1a, s2a, c2a;
        sincosf(b1[6], &s1a, &c1a);
        sincosf(b2[6], &s2a, &c2a);

        float hw1 = 0.5f * w1, hh1 = 0.5f * h1;
        float hw2 = 0.5f * w2, hh2 = 0.5f * h2;

        // corners, CCW: (-,-), (+,-), (+,+), (-,+)
        const float lox[4] = {-0.5f, 0.5f, 0.5f, -0.5f};
        const float loy[4] = {-0.5f, -0.5f, 0.5f, 0.5f};
        float c1x[4], c1y[4], c2x[4], c2y[4];
        #pragma unroll
        for (int k = 0; k < 4; ++k) {
            float sx = lox[k] * w1, sy = loy[k] * h1;
            c1x[k] = sx * c1a - sy * s1a + cx1;
            c1y[k] = sx * s1a + sy * c1a + cy1;
            float tx = lox[k] * w2, ty = loy[k] * h2;
            c2x[k] = tx * c2a - ty * s2a + cx2;
            c2y[k] = tx * s2a + ty * c2a + cy2;
        }

        // Green's theorem over the boundary of the intersection:
        // edges of box1 clipped by box2, plus edges of box2 clipped by box1.
        float area2 = 0.0f;
        #pragma unroll
        for (int k = 0; k < 4; ++k) {
            int k1 = (k + 1) & 3;
            edge_contrib(c1x[k], c1y[k], c1x[k1], c1y[k1],
                         cx2, cy2, c2a, s2a, hw2, hh2, area2);
            edge_contrib(c2x[k], c2y[k], c2x[k1], c2y[k1],
                         cx1, cy1, c1a, s1a, hw1, hh1, area2);
        }
        float inter2d = 0.5f * fabsf(area2);

        // z overlap
        float zmax1 = b1[2] + 0.5f * b1[5], zmin1 = b1[2] - 0.5f * b1[5];
        float zmax2 = b2[2] + 0.5f * b2[5], zmin2 = b2[2] - 0.5f * b2[5];
        float zo = fmaxf(fminf(zmax1, zmax2) - fmaxf(zmin1, zmin2), 0.0f);

        float inter3d = inter2d * zo;
        float v1 = b1[3] * b1[4] * b1[5];
        float v2 = b2[3] * b2[4] * b2[5];
        float denom = fmaxf(v1 + v2 - inter3d, IEPS);
        float iou = inter3d / denom;

        contrib = weight[i] * (1.0f - iou);
    }

    // wave(64) reduction
    #pragma unroll
    for (int off = 32; off > 0; off >>= 1)
        contrib += __shfl_down(contrib, off);

    __shared__ float sred[4];
    int lane = threadIdx.x & 63;
    int wid  = threadIdx.x >> 6;
    if (lane == 0) sred[wid] = contrib;
    __syncthreads();
    if (threadIdx.x == 0) {
        float s = sred[0] + sred[1] + sred[2] + sred[3];
        atomicAdd(out, s * invN);
    }
}

extern "C" void kernel_launch(void* const* d_in, const int* in_sizes, int n_in,
                              void* d_out, int out_size, void* d_ws, size_t ws_size,
                              hipStream_t stream) {
    const float* pred   = (const float*)d_in[0];
    const float* target = (const float*)d_in[1];
    const float* weight = (const float*)d_in[2];
    float* out = (float*)d_out;

    int N = in_sizes[0] / 7;
    float invN = 1.0f / (float)N;

    hipMemsetAsync(out, 0, sizeof(float), stream);

    int block = 256;
    int grid = (N + block - 1) / block;
    iou3d_loss_kernel<<<grid, block, 0, stream>>>(pred, target, weight, out, N, invN);
}

// Round 3
// 25.040 us; speedup vs baseline: 3.7590x; 1.1292x over previous
//
#include <hip/hip_runtime.h>
#include <math.h>

#define IEPS 1e-8f
#define BIGF 3.0e38f

__device__ __forceinline__ float fast_rcp(float x) { return __builtin_amdgcn_rcpf(x); }

// Clip segment p + t*d, t in [0,1], against AABB [-hw,hw] x [-hh,hh].
// Returns clamp(t1 - t0, >=0): the parameter length of the inside portion.
__device__ __forceinline__ float slab_dt(float px, float py, float dx, float dy,
                                         float hw, float hh)
{
    float rdx = fast_rcp(dx), rdy = fast_rcp(dy);
    float ax = (-hw - px) * rdx, bx = (hw - px) * rdx;
    float ay = (-hh - py) * rdy, by = (hh - py) * rdy;
    float txmin = fminf(ax, bx), txmax = fmaxf(ax, bx);
    float tymin = fminf(ay, by), tymax = fmaxf(ay, by);
    // exact-degenerate directions (avoid 0*inf NaN)
    if (dx == 0.0f) { bool in = fabsf(px) <= hw; txmin = in ? -BIGF : BIGF; txmax = in ? BIGF : -BIGF; }
    if (dy == 0.0f) { bool in = fabsf(py) <= hh; tymin = in ? -BIGF : BIGF; tymax = in ? BIGF : -BIGF; }
    float t0 = fmaxf(fmaxf(txmin, tymin), 0.0f);   // v_max3
    float t1 = fminf(fminf(txmax, tymax), 1.0f);   // v_min3
    return fmaxf(t1 - t0, 0.0f);
}

__global__ __launch_bounds__(256) void iou3d_loss_kernel(
    const float* __restrict__ pred,
    const float* __restrict__ target,
    const float* __restrict__ weight,
    float* __restrict__ out,
    int N, float invN)
{
    int i = blockIdx.x * blockDim.x + threadIdx.x;
    float contrib = 0.0f;

    if (i < N) {
        float b1[7], b2[7];
        #pragma unroll
        for (int k = 0; k < 7; ++k) { b1[k] = pred[i * 7 + k]; b2[k] = target[i * 7 + k]; }

        float cx1 = b1[0], cy1 = b1[1], hw1 = 0.5f * b1[3], hh1 = 0.5f * b1[4];
        float cx2 = b2[0], cy2 = b2[1], hw2 = 0.5f * b2[3], hh2 = 0.5f * b2[4];
        float c1a = __cosf(b1[6]), s1a = __sinf(b1[6]);
        float c2a = __cosf(b2[6]), s2a = __sinf(b2[6]);

        // center offset rotated into each frame
        float dxg = cx2 - cx1, dyg = cy2 - cy1;
        float t12x =  dxg * c1a + dyg * s1a;     // box2 center in frame1
        float t12y = -dxg * s1a + dyg * c1a;
        float t21x = -(dxg * c2a + dyg * s2a);   // box1 center in frame2
        float t21y = -(-dxg * s2a + dyg * c2a);
        // relative rotation r = a2 - a1
        float cr = c2a * c1a + s2a * s1a;
        float sr = s2a * c1a - c2a * s1a;

        const float sgx[4] = {-1.0f, 1.0f, 1.0f, -1.0f};
        const float sgy[4] = {-1.0f, -1.0f, 1.0f, 1.0f};

        float q1x[4], q1y[4];  // box2 corners in frame1
        float p2x[4], p2y[4];  // box1 corners in frame2
        #pragma unroll
        for (int k = 0; k < 4; ++k) {
            float ux = sgx[k] * hw2, uy = sgy[k] * hh2;
            q1x[k] = t12x + ux * cr - uy * sr;   // R(+r)
            q1y[k] = t12y + ux * sr + uy * cr;
            float vx = sgx[k] * hw1, vy = sgy[k] * hh1;
            p2x[k] = t21x + vx * cr + vy * sr;   // R(-r)
            p2y[k] = t21y - vx * sr + vy * cr;
        }

        // Green's theorem, all cross terms in frame2 (closed loop -> frame-invariant):
        // box1 edges clipped by box2's AABB; contribution (t1-t0)*cross(p,d)
        float area2 = 0.0f;
        float sum_dt2 = 0.0f;
        #pragma unroll
        for (int k = 0; k < 4; ++k) {
            int k1 = (k + 1) & 3;
            float dx = p2x[k1] - p2x[k], dy = p2y[k1] - p2y[k];
            float dt = slab_dt(p2x[k], p2y[k], dx, dy, hw2, hh2);
            area2 += dt * (p2x[k] * dy - p2y[k] * dx);
            // box2 edges clipped by box1's AABB (in frame1); cross(p,d) in frame2
            // is the constant 2*hw2*hh2 for every edge of box2
            float ex = q1x[k1] - q1x[k], ey = q1y[k1] - q1y[k];
            sum_dt2 += slab_dt(q1x[k], q1y[k], ex, ey, hw1, hh1);
        }
        area2 += 2.0f * hw2 * hh2 * sum_dt2;
        float inter2d = 0.5f * fabsf(area2);

        // z overlap
        float hz1 = 0.5f * b1[5], hz2 = 0.5f * b2[5];
        float zo = fmaxf(fminf(b1[2] + hz1, b2[2] + hz2) - fmaxf(b1[2] - hz1, b2[2] - hz2), 0.0f);

        float inter3d = inter2d * zo;
        float v1 = b1[3] * b1[4] * b1[5];
        float v2 = b2[3] * b2[4] * b2[5];
        float denom = fmaxf(v1 + v2 - inter3d, IEPS);
        float iou = inter3d / denom;

        contrib = weight[i] * (1.0f - iou);
    }

    // wave(64) reduction
    #pragma unroll
    for (int off = 32; off > 0; off >>= 1)
        contrib += __shfl_down(contrib, off);

    __shared__ float sred[4];
    int lane = threadIdx.x & 63;
    int wid  = threadIdx.x >> 6;
    if (lane == 0) sred[wid] = contrib;
    __syncthreads();
    if (threadIdx.x == 0) {
        float s = sred[0] + sred[1] + sred[2] + sred[3];
        atomicAdd(out, s * invN);
    }
}

extern "C" void kernel_launch(void* const* d_in, const int* in_sizes, int n_in,
                              void* d_out, int out_size, void* d_ws, size_t ws_size,
                              hipStream_t stream) {
    const float* pred   = (const float*)d_in[0];
    const float* target = (const float*)d_in[1];
    const float* weight = (const float*)d_in[2];
    float* out = (float*)d_out;

    int N = in_sizes[0] / 7;
    float invN = 1.0f / (float)N;

    hipMemsetAsync(out, 0, sizeof(float), stream);

    int block = 256;
    int grid = (N + block - 1) / block;
    iou3d_loss_kernel<<<grid, block, 0, stream>>>(pred, target, weight, out, N, invN);
}

// Round 4
// 10.891 us; speedup vs baseline: 8.6422x; 2.2991x over previous
//
#include <hip/hip_runtime.h>
#include <math.h>

#define IEPS 1e-8f
#define BIGF 3.0e38f

typedef float f4 __attribute__((ext_vector_type(4)));
struct __attribute__((packed, aligned(4))) F4u { f4 v; };

__device__ __forceinline__ float fast_rcp(float x) { return __builtin_amdgcn_rcpf(x); }

// Clip segment p + t*d, t in [0,1], against AABB [-hw,hw] x [-hh,hh].
// Returns clamp(t1 - t0, >=0): parameter length of the inside portion.
__device__ __forceinline__ float slab_dt(float px, float py, float dx, float dy,
                                         float hw, float hh)
{
    float rdx = fast_rcp(dx), rdy = fast_rcp(dy);
    float ax = (-hw - px) * rdx, bx = (hw - px) * rdx;
    float ay = (-hh - py) * rdy, by = (hh - py) * rdy;
    float txmin = fminf(ax, bx), txmax = fmaxf(ax, bx);
    float tymin = fminf(ay, by), tymax = fmaxf(ay, by);
    if (dx == 0.0f) { bool in = fabsf(px) <= hw; txmin = in ? -BIGF : BIGF; txmax = in ? BIGF : -BIGF; }
    if (dy == 0.0f) { bool in = fabsf(py) <= hh; tymin = in ? -BIGF : BIGF; tymax = in ? BIGF : -BIGF; }
    float t0 = fmaxf(fmaxf(txmin, tymin), 0.0f);   // v_max3
    float t1 = fminf(fminf(txmax, tymax), 1.0f);   // v_min3
    return fmaxf(t1 - t0, 0.0f);
}

__global__ __launch_bounds__(256) void iou3d_partial_kernel(
    const float* __restrict__ pred,
    const float* __restrict__ target,
    const float* __restrict__ weight,
    float* __restrict__ partial,
    int N)
{
    int i = blockIdx.x * blockDim.x + threadIdx.x;
    float contrib = 0.0f;

    if (i < N) {
        // overlapping dwordx4 loads: floats [0..3] and [3..6] of each box
        const float* P = pred + (size_t)i * 7;
        const float* T = target + (size_t)i * 7;
        f4 pA = ((const F4u*)P)->v;          // x, y, z, dx
        f4 pB = ((const F4u*)(P + 3))->v;    // dx, dy, dz, yaw
        f4 tA = ((const F4u*)T)->v;
        f4 tB = ((const F4u*)(T + 3))->v;

        float cx1 = pA[0], cy1 = pA[1], z1 = pA[2];
        float w1 = pA[3], h1 = pB[1], dz1 = pB[2], yaw1 = pB[3];
        float cx2 = tA[0], cy2 = tA[1], z2 = tA[2];
        float w2 = tA[3], h2 = tB[1], dz2 = tB[2], yaw2 = tB[3];

        float hw1 = 0.5f * w1, hh1 = 0.5f * h1;
        float hw2 = 0.5f * w2, hh2 = 0.5f * h2;
        float c1a = __cosf(yaw1), s1a = __sinf(yaw1);
        float c2a = __cosf(yaw2), s2a = __sinf(yaw2);

        // center offset rotated into each frame
        float dxg = cx2 - cx1, dyg = cy2 - cy1;
        float t12x =  dxg * c1a + dyg * s1a;     // box2 center in frame1
        float t12y = -dxg * s1a + dyg * c1a;
        float t21x = -(dxg * c2a + dyg * s2a);   // box1 center in frame2
        float t21y = -(-dxg * s2a + dyg * c2a);
        // relative rotation r = a2 - a1
        float cr = c2a * c1a + s2a * s1a;
        float sr = s2a * c1a - c2a * s1a;

        const float sgx[4] = {-1.0f, 1.0f, 1.0f, -1.0f};
        const float sgy[4] = {-1.0f, -1.0f, 1.0f, 1.0f};

        float q1x[4], q1y[4];  // box2 corners in frame1
        float p2x[4], p2y[4];  // box1 corners in frame2
        #pragma unroll
        for (int k = 0; k < 4; ++k) {
            float ux = sgx[k] * hw2, uy = sgy[k] * hh2;
            q1x[k] = t12x + ux * cr - uy * sr;   // R(+r)
            q1y[k] = t12y + ux * sr + uy * cr;
            float vx = sgx[k] * hw1, vy = sgy[k] * hh1;
            p2x[k] = t21x + vx * cr + vy * sr;   // R(-r)
            p2y[k] = t21y - vx * sr + vy * cr;
        }

        // Green's theorem over the intersection boundary, evaluated in frame2.
        float area2 = 0.0f;
        float sum_dt2 = 0.0f;
        #pragma unroll
        for (int k = 0; k < 4; ++k) {
            int k1 = (k + 1) & 3;
            float dx = p2x[k1] - p2x[k], dy = p2y[k1] - p2y[k];
            float dt = slab_dt(p2x[k], p2y[k], dx, dy, hw2, hh2);
            area2 += dt * (p2x[k] * dy - p2y[k] * dx);
            // box2's own edges: cross(p,d) == 2*hw2*hh2 constant in frame2
            float ex = q1x[k1] - q1x[k], ey = q1y[k1] - q1y[k];
            sum_dt2 += slab_dt(q1x[k], q1y[k], ex, ey, hw1, hh1);
        }
        area2 += 2.0f * hw2 * hh2 * sum_dt2;
        float inter2d = 0.5f * fabsf(area2);

        // z overlap
        float hz1 = 0.5f * dz1, hz2 = 0.5f * dz2;
        float zo = fmaxf(fminf(z1 + hz1, z2 + hz2) - fmaxf(z1 - hz1, z2 - hz2), 0.0f);

        float inter3d = inter2d * zo;
        float v1 = w1 * h1 * dz1;
        float v2 = w2 * h2 * dz2;
        float denom = fmaxf(v1 + v2 - inter3d, IEPS);
        float iou = inter3d / denom;

        contrib = weight[i] * (1.0f - iou);
    }

    // wave(64) reduction
    #pragma unroll
    for (int off = 32; off > 0; off >>= 1)
        contrib += __shfl_down(contrib, off);

    __shared__ float sred[4];
    int lane = threadIdx.x & 63;
    int wid  = threadIdx.x >> 6;
    if (lane == 0) sred[wid] = contrib;
    __syncthreads();
    if (threadIdx.x == 0)
        partial[blockIdx.x] = sred[0] + sred[1] + sred[2] + sred[3];
}

__global__ __launch_bounds__(1024) void iou3d_reduce_kernel(
    const float* __restrict__ partial, float* __restrict__ out,
    int nPart, float invN)
{
    int t = threadIdx.x;
    float s = 0.0f;
    for (int k = t; k < nPart; k += 1024) s += partial[k];

    #pragma unroll
    for (int off = 32; off > 0; off >>= 1)
        s += __shfl_down(s, off);

    __shared__ float sm[16];
    if ((t & 63) == 0) sm[t >> 6] = s;
    __syncthreads();
    if (t == 0) {
        float tot = 0.0f;
        #pragma unroll
        for (int k = 0; k < 16; ++k) tot += sm[k];
        out[0] = tot * invN;
    }
}

extern "C" void kernel_launch(void* const* d_in, const int* in_sizes, int n_in,
                              void* d_out, int out_size, void* d_ws, size_t ws_size,
                              hipStream_t stream) {
    const float* pred   = (const float*)d_in[0];
    const float* target = (const float*)d_in[1];
    const float* weight = (const float*)d_in[2];
    float* out = (float*)d_out;
    float* partial = (float*)d_ws;

    int N = in_sizes[0] / 7;
    float invN = 1.0f / (float)N;

    int block = 256;
    int grid = (N + block - 1) / block;   // 1024 for N=262144
    iou3d_partial_kernel<<<grid, block, 0, stream>>>(pred, target, weight, partial, N);
    iou3d_reduce_kernel<<<1, 1024, 0, stream>>>(partial, out, grid, invN);
}